// Round 2
// baseline (44.875 us; speedup 1.0000x reference)
//
#include <hip/hip_runtime.h>

#define CLS 512
#define NROWS 32768
#define WPB 4
#define NBLOCKS 2048   // 2048 blocks * 4 waves * 4 rows/wave = 32768 rows, one shot

__global__ __launch_bounds__(256) void lr_kernel(
    const float* __restrict__ out, const int* __restrict__ tgt,
    float* __restrict__ loss) {
  const int lane = threadIdx.x & 63;
  const int s    = lane & 15;                       // sub-lane within 16-lane group
  const int gw   = blockIdx.x * WPB + (threadIdx.x >> 6);
  const int row  = gw * 4 + (lane >> 4);            // each 16-lane group owns one row

  const float* op = out + (size_t)row * CLS + s * 4;
  const int*   tp = tgt + (size_t)row * CLS + s * 4;

  float s_neg = 0.0f, s_pos = 0.0f, np = 0.0f;
#pragma unroll
  for (int p = 0; p < 8; ++p) {
    float4 o = *reinterpret_cast<const float4*>(op + p * 64);
    int4   t = *reinterpret_cast<const int4*>(tp + p * 64);
    float ov[4] = {o.x, o.y, o.z, o.w};
    int   tv[4] = {t.x, t.y, t.z, t.w};
#pragma unroll
    for (int j = 0; j < 4; ++j) {
      float e = __expf(tv[j] ? -ov[j] : ov[j]);
      s_pos += tv[j] ? e : 0.0f;
      s_neg += tv[j] ? 0.0f : e;
      np    += tv[j] ? 1.0f : 0.0f;
    }
  }

  // 4-step butterfly within each 16-lane group (serves 4 rows at once)
#pragma unroll
  for (int m = 1; m < 16; m <<= 1) {
    s_neg += __shfl_xor(s_neg, m);
    s_pos += __shfl_xor(s_pos, m);
    np    += __shfl_xor(np, m);
  }

  float fneg = (float)CLS - np;
  float num  = np * fneg;
  if (num == 0.0f) num = (float)CLS;
  float c = (s == 0) ? s_neg * s_pos / num : 0.0f;  // lanes 0,16,32,48 hold row results

  // sum the 4 group-leader values across the wave (2 shuffles)
  c += __shfl_xor(c, 16);
  c += __shfl_xor(c, 32);

  __shared__ float sacc[WPB];
  if (lane == 0) sacc[threadIdx.x >> 6] = c;
  __syncthreads();
  if (threadIdx.x == 0) {
    float t = sacc[0] + sacc[1] + sacc[2] + sacc[3];
    atomicAdd(loss, t);   // 2048 adds total; reorder eps << 1781 threshold
  }
}

extern "C" void kernel_launch(void* const* d_in, const int* in_sizes, int n_in,
                              void* d_out, int out_size, void* d_ws, size_t ws_size,
                              hipStream_t stream) {
  const float* output = (const float*)d_in[0];
  const int*   target = (const int*)d_in[1];
  float* loss = (float*)d_out;

  hipMemsetAsync(loss, 0, sizeof(float), stream);
  lr_kernel<<<NBLOCKS, 256, 0, stream>>>(output, target, loss);
}

// Round 3
// 27.587 us; speedup vs baseline: 1.6267x; 1.6267x over previous
//
#include <hip/hip_runtime.h>

#define CLS 512
#define NROWS 32768
#define WPB 4
#define NBLOCKS 2048   // 2048 blocks * 4 waves * 4 rows/wave = 32768 rows, one shot

__global__ __launch_bounds__(256) void lr_main_kernel(
    const float* __restrict__ out, const int* __restrict__ tgt,
    float* __restrict__ partial) {
  const int lane = threadIdx.x & 63;
  const int wid  = threadIdx.x >> 6;
  const int gw   = blockIdx.x * WPB + wid;          // 0..8191
  const size_t base = (size_t)gw * 4 * CLS;         // 4 consecutive rows per wave

  const float4* po = reinterpret_cast<const float4*>(out + base);
  const int4*   pt = reinterpret_cast<const int4*>(tgt + base);

  // Row r occupies float4 indices [r*128, r*128+128). Each of the 16 loads is
  // a full-wave contiguous 1KB read. Hoist ALL loads so they are in flight
  // together (one latency exposure per wave).
  float4 o[8];
  int4   t[8];
#pragma unroll
  for (int r = 0; r < 4; ++r) {
    o[2 * r]     = po[r * 128 + lane];
    o[2 * r + 1] = po[r * 128 + 64 + lane];
    t[2 * r]     = pt[r * 128 + lane];
    t[2 * r + 1] = pt[r * 128 + 64 + lane];
  }

  float acc = 0.0f;
#pragma unroll
  for (int r = 0; r < 4; ++r) {
    float s_neg = 0.0f, s_pos = 0.0f, np = 0.0f;
#pragma unroll
    for (int k = 0; k < 2; ++k) {
      float4 ov = o[2 * r + k];
      int4   tv = t[2 * r + k];
      float vx[4] = {ov.x, ov.y, ov.z, ov.w};
      int   mx[4] = {tv.x, tv.y, tv.z, tv.w};
#pragma unroll
      for (int j = 0; j < 4; ++j) {
        float e = __expf(mx[j] ? -vx[j] : vx[j]);
        s_pos += mx[j] ? e : 0.0f;
        s_neg += mx[j] ? 0.0f : e;
        np    += mx[j] ? 1.0f : 0.0f;
      }
    }
    // 6-step butterfly; the 4 rows' chains are independent -> ILP
#pragma unroll
    for (int m = 1; m < 64; m <<= 1) {
      s_neg += __shfl_xor(s_neg, m);
      s_pos += __shfl_xor(s_pos, m);
      np    += __shfl_xor(np, m);
    }
    float num = np * ((float)CLS - np);
    if (num == 0.0f) num = (float)CLS;
    acc += s_neg * s_pos / num;     // same in every lane
  }

  __shared__ float sacc[WPB];
  if (lane == 0) sacc[wid] = acc;
  __syncthreads();
  if (threadIdx.x == 0)
    partial[blockIdx.x] = sacc[0] + sacc[1] + sacc[2] + sacc[3];
}

__global__ __launch_bounds__(256) void lr_final_kernel(
    const float* __restrict__ partial, float* __restrict__ out) {
  const int lane = threadIdx.x & 63;
  const int wid  = threadIdx.x >> 6;

  float s = 0.0f;
#pragma unroll
  for (int i = threadIdx.x; i < NBLOCKS; i += 256) s += partial[i];

#pragma unroll
  for (int m = 1; m < 64; m <<= 1) s += __shfl_xor(s, m);

  __shared__ float w[4];
  if (lane == 0) w[wid] = s;
  __syncthreads();
  if (threadIdx.x == 0) out[0] = w[0] + w[1] + w[2] + w[3];
}

extern "C" void kernel_launch(void* const* d_in, const int* in_sizes, int n_in,
                              void* d_out, int out_size, void* d_ws, size_t ws_size,
                              hipStream_t stream) {
  const float* output = (const float*)d_in[0];
  const int*   target = (const int*)d_in[1];
  float* partial = (float*)d_ws;          // NBLOCKS floats = 8 KiB
  float* loss    = (float*)d_out;

  lr_main_kernel<<<NBLOCKS, 256, 0, stream>>>(output, target, partial);
  lr_final_kernel<<<1, 256, 0, stream>>>(partial, loss);
}